// Round 1
// baseline (36.088 us; speedup 1.0000x reference)
//
#include <hip/hip_runtime.h>
#include <cmath>

#define BB 32768
#define CC 1000
#define NF4 250   // CC/4 float4 chunks per row
#define NBLK 8192 // BB/4 rows-per-block

__device__ __forceinline__ float wave_reduce_sum(float v) {
  #pragma unroll
  for (int m = 32; m >= 1; m >>= 1) v += __shfl_xor(v, m, 64);
  return v;
}
__device__ __forceinline__ float wave_reduce_max(float v) {
  #pragma unroll
  for (int m = 32; m >= 1; m >>= 1) v = fmaxf(v, __shfl_xor(v, m, 64));
  return v;
}

// One 64-lane wave per row; 4 waves (4 rows) per 256-thread block.
__global__ __launch_bounds__(256) void hfl_rows(
    const float* __restrict__ x, const int* __restrict__ tgt,
    float* __restrict__ class_sum, float* __restrict__ class_cnt,
    float* __restrict__ pfocal, float* __restrict__ ps2) {
  const int wave = threadIdx.x >> 6;
  const int lane = threadIdx.x & 63;
  const int row  = (blockIdx.x << 2) + wave;

  const float4* rp = reinterpret_cast<const float4*>(x + (size_t)row * CC);
  const int t = tgt[row];

  float4 v[4];
  bool valid[4];
  float vmax = -INFINITY;
  #pragma unroll
  for (int k = 0; k < 4; ++k) {
    const int f4 = (k << 6) + lane;
    valid[k] = (f4 < NF4);
    if (valid[k]) {
      v[k] = rp[f4];
      vmax = fmaxf(vmax, fmaxf(fmaxf(v[k].x, v[k].y), fmaxf(v[k].z, v[k].w)));
    }
  }
  const float rowmax = wave_reduce_max(vmax);

  float se = 0.f, s = 0.f, s2 = 0.f, g = 0.f;
  #pragma unroll
  for (int k = 0; k < 4; ++k) {
    if (valid[k]) {
      const int c0 = (((k << 6) + lane) << 2);
      const float a = v[k].x, b = v[k].y, c = v[k].z, d = v[k].w;
      se += __expf(a - rowmax) + __expf(b - rowmax)
          + __expf(c - rowmax) + __expf(d - rowmax);
      s  += (a + b) + (c + d);
      s2 += (a * a + b * b) + (c * c + d * d);
      if (t >= c0 && t < c0 + 4) {
        const int dd = t - c0;
        g = (dd == 0) ? a : (dd == 1) ? b : (dd == 2) ? c : d;
      }
    }
  }
  se = wave_reduce_sum(se);
  s  = wave_reduce_sum(s);
  s2 = wave_reduce_sum(s2);
  g  = wave_reduce_sum(g);   // exactly one lane contributed x[row,t]

  __shared__ float sh_f[4], sh_s2[4];
  if (lane == 0) {
    const float lse = rowmax + __logf(se);
    const float ce  = lse - 0.9f * g - 0.1f * (s * (1.0f / CC));
    const float pt  = __expf(-ce);
    const float omp = 1.0f - pt;
    sh_f[wave]  = omp * omp * ce;   // ALPHA=1, GAMMA=2
    sh_s2[wave] = s2;
    atomicAdd(&class_sum[t], g);
    atomicAdd(&class_cnt[t], 1.0f);
  }
  __syncthreads();
  if (threadIdx.x == 0) {
    pfocal[blockIdx.x] = (sh_f[0] + sh_f[1]) + (sh_f[2] + sh_f[3]);
    ps2[blockIdx.x]    = (sh_s2[0] + sh_s2[1]) + (sh_s2[2] + sh_s2[3]);
  }
}

// Single-block finisher: reduce 8192 block partials + 1000-class center term.
__global__ __launch_bounds__(1024) void hfl_final(
    const float* __restrict__ class_sum, const float* __restrict__ class_cnt,
    const float* __restrict__ pfocal, const float* __restrict__ ps2,
    float* __restrict__ out) {
  const int tid = threadIdx.x;
  float f = 0.f, s2 = 0.f, ct = 0.f;
  #pragma unroll 2
  for (int i = tid; i < NBLK; i += 1024) { f += pfocal[i]; s2 += ps2[i]; }
  for (int c = tid; c < CC; c += 1024) {
    const float cnt = class_cnt[c];
    if (cnt > 0.f) {
      const float sm = class_sum[c];
      const float m  = sm / cnt;
      // 2*Σ_i g_i m_i  -  Σ_i m_i²  aggregated per class
      ct += 2.0f * m * sm - cnt * m * m;
    }
  }
  f  = wave_reduce_sum(f);
  s2 = wave_reduce_sum(s2);
  ct = wave_reduce_sum(ct);

  __shared__ float shf[16], shs[16], shc[16];
  const int wave = tid >> 6, lane = tid & 63;
  if (lane == 0) { shf[wave] = f; shs[wave] = s2; shc[wave] = ct; }
  __syncthreads();
  if (tid == 0) {
    float F = 0.f, S = 0.f, T = 0.f;
    #pragma unroll
    for (int w = 0; w < 16; ++w) { F += shf[w]; S += shs[w]; T += shc[w]; }
    const float center = (S - T) * (1.0f / ((float)BB * (float)CC));
    out[0] = F * (1.0f / (float)BB) + 0.1f * center;
  }
}

extern "C" void kernel_launch(void* const* d_in, const int* in_sizes, int n_in,
                              void* d_out, int out_size, void* d_ws, size_t ws_size,
                              hipStream_t stream) {
  const float* x   = (const float*)d_in[0];
  const int*   tgt = (const int*)d_in[1];
  float* out = (float*)d_out;

  // d_ws layout (bytes): [0,4096) class_sum  [4096,8192) class_cnt
  //                      [8192,40960) pfocal [40960,73728) ps2
  float* class_sum = (float*)d_ws;
  float* class_cnt = (float*)((char*)d_ws + 4096);
  float* pfocal    = (float*)((char*)d_ws + 8192);
  float* ps2       = (float*)((char*)d_ws + 8192 + NBLK * 4);

  // d_ws is poisoned once and never re-poisoned; zero the atomic tables
  // ourselves every call (partials are fully overwritten, no need).
  hipMemsetAsync(d_ws, 0, 8192, stream);

  hfl_rows<<<NBLK, 256, 0, stream>>>(x, tgt, class_sum, class_cnt, pfocal, ps2);
  hfl_final<<<1, 1024, 0, stream>>>(class_sum, class_cnt, pfocal, ps2, out);
}